// Round 6
// baseline (112.340 us; speedup 1.0000x reference)
//
#include <hip/hip_runtime.h>

// N=32, CIN=64, COUT=128, K=4, H=W=64
#define Nn     32
#define CIN    64
#define COUT   128
#define HWVOL  4096                 // H*W
#define PLANES (Nn * CIN)           // 2048 blocks, one x-plane each
#define OHW_INV (1.0f / 4489.0f)    // 1/67^2
#define NEGBIG (-3.0e38f)
#define MAGIC  0x5EC7A5A1u          // distinct bytes: no byte-pattern poison can match

// ---------------------------------------------------------------------------
// Single-dispatch, zero-fence, LEAN-TAIL fused kernel.
//   R2: agent __threadfence = whole-L2 writeback -> banned.
//   R4: 33KB LDS (4 blk/CU streaming) + 262K RMW fetches -> slow tail.
//   R5: sw_reg[32]+wb[8] under (256,8) -> VGPR>64 -> scratch spills.
// This version: tail uses NO Sw LDS and NO register arrays -- thread co
// accumulates straight from Sw64[ci*128+co] via batched (8-deep) agent-scope
// atomic LOADS (coalesced across lanes, pipelined). LDS ~600B, VGPR ~40
// -> true 8 blocks/CU for the 32MB streaming phase AND a sub-microsecond tail.
//
// Publish (proven R3-R5): each value is ONE packed u64 {hi=MAGIC, lo=bits}
// via agent-scope atomic exchange -- data+flag in one word, no ordering needed.
// Consumers use agent-scope atomic loads (coherent, proven in R2-R5 polls).
//
// Block b (0..2047): blocks 0..31 first publish a 256-value Sw chunk (exact
// R0 tree); every block then sums x-plane b (exact R0 tree) -> Sx64[b];
// blocks 0..31 then poll the 64 Sx words of image n=b, and run the GEMV in
// EXACT ci=0..63 order (bit-identical to the proven 79us kernel) + logsumexp.
//
// Deadlock-free: producers never wait; only 32/2048 blocks wait (and they are
// the first dispatched); all spins iteration-bounded.
// ---------------------------------------------------------------------------
__global__ __launch_bounds__(256, 8) void fused_kernel(
    const float* __restrict__ x,
    const float* __restrict__ w,
    const float* __restrict__ conv_bias,
    const float* __restrict__ extra_bias,
    unsigned long long* __restrict__ Sx64,
    unsigned long long* __restrict__ Sw64,
    float* __restrict__ out)
{
    const int b = blockIdx.x;
    const int t = threadIdx.x;

    __shared__ float sxs[CIN];
    __shared__ float part[4];
    __shared__ float wm[4], wl[4];

    // ---- Sw chunk (blocks 0..31, published before anything else)
    if (b < 32) {
        const int o = b * 256 + t;                   // 0..8191 = ci*128+co
        const float4* wp = (const float4*)(w + (size_t)o * 16);
        float4 a = wp[0], c = wp[1], d = wp[2], e = wp[3];
        const float sw =
            (((a.x + a.y) + (a.z + a.w)) + ((c.x + c.y) + (c.z + c.w))) +
            (((d.x + d.y) + (d.z + d.w)) + ((e.x + e.y) + (e.z + e.w)));
        const unsigned long long word =
            ((unsigned long long)MAGIC << 32) | (unsigned long long)__float_as_uint(sw);
        __hip_atomic_exchange(&Sw64[o], word, __ATOMIC_RELAXED,
                              __HIP_MEMORY_SCOPE_AGENT);
    }

    // ---- Phase A: one x-plane sum per block (exact R0 tree), publish 1 word
    {
        const float4* xp = (const float4*)(x + (size_t)b * HWVOL);
        float acc = 0.0f;
#pragma unroll
        for (int j = 0; j < 4; ++j) {
            float4 v = xp[t + 256 * j];
            acc += (v.x + v.y) + (v.z + v.w);
        }
#pragma unroll
        for (int off = 32; off > 0; off >>= 1)
            acc += __shfl_down(acc, off, 64);
        if ((t & 63) == 0) part[t >> 6] = acc;
        __syncthreads();
        if (t == 0) {
            const float s = (part[0] + part[1]) + (part[2] + part[3]);
            const unsigned long long word =
                ((unsigned long long)MAGIC << 32) | (unsigned long long)__float_as_uint(s);
            __hip_atomic_exchange(&Sx64[b], word, __ATOMIC_RELAXED,
                                  __HIP_MEMORY_SCOPE_AGENT);
        }
    }

    // ---- Phase B: blocks 0..31 consume; block n -> out[n]
    if (b >= Nn) return;
    const int n = b;

    // Poll the 64 plane words of image n (agent atomic loads: coherent, cheap)
    if (t < CIN) {
        const int idx = n * CIN + t;
        unsigned long long word;
        int spins = 0;
        for (;;) {
            word = __hip_atomic_load(&Sx64[idx], __ATOMIC_RELAXED,
                                     __HIP_MEMORY_SCOPE_AGENT);
            if ((unsigned)(word >> 32) == MAGIC) break;
            __builtin_amdgcn_s_sleep(1);
            if (++spins > (1 << 18)) break;   // bounded: fail loudly, never hang
        }
        sxs[t] = __uint_as_float((unsigned)word);
    }
    __syncthreads();

    // GEMV straight from Sw64: thread co reads Sw64[ci*128+co] (coalesced
    // across lanes), 8 independent loads in flight per batch, accumulated in
    // EXACT ci = 0..63 sequential order (bit-identical to the proven kernel).
    float pooled = NEGBIG;
    if (t < COUT) {
        const int co = t;
        float acc = 0.0f;
#pragma unroll
        for (int g = 0; g < 8; ++g) {
            unsigned long long wb[8];
#pragma unroll
            for (int j = 0; j < 8; ++j)
                wb[j] = __hip_atomic_load(&Sw64[(g * 8 + j) * COUT + co],
                                          __ATOMIC_RELAXED, __HIP_MEMORY_SCOPE_AGENT);
#pragma unroll
            for (int j = 0; j < 8; ++j) {
                int spins = 0;
                while ((unsigned)(wb[j] >> 32) != MAGIC) {   // almost never taken
                    __builtin_amdgcn_s_sleep(1);
                    wb[j] = __hip_atomic_load(&Sw64[(g * 8 + j) * COUT + co],
                                              __ATOMIC_RELAXED, __HIP_MEMORY_SCOPE_AGENT);
                    if (++spins > (1 << 18)) break;
                }
                acc = fmaf(sxs[g * 8 + j], __uint_as_float((unsigned)wb[j]), acc);
            }
        }
        pooled = acc * OHW_INV + conv_bias[co] + extra_bias[co];
    }

    // logsumexp across 128 live lanes (4 waves; waves 2,3 hold NEGBIG -> exp->0)
    float m = pooled;
#pragma unroll
    for (int off = 32; off > 0; off >>= 1)
        m = fmaxf(m, __shfl_xor(m, off, 64));
    if ((t & 63) == 0) wm[t >> 6] = m;
    __syncthreads();
    m = fmaxf(fmaxf(wm[0], wm[1]), fmaxf(wm[2], wm[3]));

    float e = __expf(pooled - m);
#pragma unroll
    for (int off = 32; off > 0; off >>= 1)
        e += __shfl_xor(e, off, 64);
    if ((t & 63) == 0) wl[t >> 6] = e;
    __syncthreads();
    if (t == 0) out[n] = 10.0f * (m + logf((wl[0] + wl[1]) + (wl[2] + wl[3])));
}

extern "C" void kernel_launch(void* const* d_in, const int* in_sizes, int n_in,
                              void* d_out, int out_size, void* d_ws, size_t ws_size,
                              hipStream_t stream) {
    const float* x          = (const float*)d_in[0];
    const float* weight     = (const float*)d_in[1];
    const float* conv_bias  = (const float*)d_in[2];
    const float* extra_bias = (const float*)d_in[3];
    float* out = (float*)d_out;

    unsigned long long* Sx64 = (unsigned long long*)d_ws;   // 2048 u64
    unsigned long long* Sw64 = Sx64 + PLANES;               // 8192 u64

    fused_kernel<<<PLANES, 256, 0, stream>>>(x, weight, conv_bias, extra_bias,
                                             Sx64, Sw64, out);
}

// Round 7
// 78.919 us; speedup vs baseline: 1.4235x; 1.4235x over previous
//
#include <hip/hip_runtime.h>

// N=32, CIN=64, COUT=128, K=4, H=W=64
#define Nn     32
#define CIN    64
#define COUT   128
#define HWVOL  4096                 // H*W
#define PLANES (Nn * CIN)           // 2048
#define WBLKS  ((CIN * COUT) / 256) // 32 blocks for the weight sums
#define OHW_INV (1.0f / 4489.0f)    // 1/67^2

// ---------------------------------------------------------------------------
// PROVEN BEST (R0, 79.05 us, absmax 0.0). Reverted after R1-R6 established
// that single-dispatch fusion cannot win on this chip:
//   - cg grid.sync:           ~70 us barrier stall            (R1)
//   - agent __threadfence:    whole-L2 writeback, ~100 us     (R2)
//   - consumer recompute Sw:  16 MB cold read by thin blocks  (R3)
//   - fetch_add(0) Sw pull:   262K RMWs at coherence point    (R4)
//   - reg-array under (256,8): VGPR>64 -> scratch spills      (R5)
//   - u64 atomic-load Sw pull: WRITE_SIZE==262144*8B proves loads
//     service at L3/MALL (per-XCD L2 non-coherent); 40 us tail (R6)
// Cross-block transport of Sw via coherence-point ops costs 10-40 us,
// always exceeding the ~2-4 us launch gap fusion saves.
//
// Stage 1 (single launch, no internal dependency):
//   blocks [0, 2048):    Sx[g] = sum of x-plane g   (16 KB coalesced read)
//   blocks [2048, 2080): Sw[o] = sum of 16 kernel taps, o = (b-2048)*256 + t
// Small LDS (16 B) -> full occupancy for the streaming phase.
// ---------------------------------------------------------------------------
__global__ __launch_bounds__(256) void stage1_kernel(
    const float* __restrict__ x,
    const float* __restrict__ w,
    float* __restrict__ Sx,
    float* __restrict__ Sw)
{
    const int b = blockIdx.x;
    const int t = threadIdx.x;

    if (b < PLANES) {
        const float4* xp = (const float4*)(x + (size_t)b * HWVOL);
        float acc = 0.0f;
#pragma unroll
        for (int j = 0; j < 4; ++j) {
            float4 v = xp[t + 256 * j];
            acc += (v.x + v.y) + (v.z + v.w);
        }
#pragma unroll
        for (int off = 32; off > 0; off >>= 1)
            acc += __shfl_down(acc, off, 64);
        __shared__ float part[4];
        if ((t & 63) == 0) part[t >> 6] = acc;
        __syncthreads();
        if (t == 0) Sx[b] = (part[0] + part[1]) + (part[2] + part[3]);
    } else {
        const int o = (b - PLANES) * 256 + t;   // 0..8191
        const float4* wp = (const float4*)(w + (size_t)o * 16);
        float4 a = wp[0], c = wp[1], d = wp[2], e = wp[3];
        Sw[o] = (((a.x + a.y) + (a.z + a.w)) + ((c.x + c.y) + (c.z + c.w))) +
                (((d.x + d.y) + (d.z + d.w)) + ((e.x + e.y) + (e.z + e.w)));
    }
}

// ---------------------------------------------------------------------------
// Stage 2: one block per image n, 128 threads = one per co.
//   pooled[co] = (sum_ci Sx[n,ci]*Sw[ci,co]) / 4489 + conv_bias + extra_bias
//   out[n]    = 10 * logsumexp_co(pooled)
// Sw reads coalesced (stride COUT across lanes); ~32 KB per block, L2-hot.
// ---------------------------------------------------------------------------
__global__ __launch_bounds__(128) void final_kernel(
    const float* __restrict__ Sx,
    const float* __restrict__ Sw,
    const float* __restrict__ conv_bias,
    const float* __restrict__ extra_bias,
    float* __restrict__ out)
{
    const int n  = blockIdx.x;
    const int co = threadIdx.x;
    __shared__ float sxs[CIN];
    if (co < CIN) sxs[co] = Sx[n * CIN + co];
    __syncthreads();

    float acc = 0.0f;
#pragma unroll
    for (int ci = 0; ci < CIN; ++ci)
        acc = fmaf(sxs[ci], Sw[ci * COUT + co], acc);

    const float pooled = acc * OHW_INV + conv_bias[co] + extra_bias[co];

    // logsumexp over 128 lanes: 2 waves -> LDS combine
    float m = pooled;
#pragma unroll
    for (int off = 32; off > 0; off >>= 1)
        m = fmaxf(m, __shfl_xor(m, off, 64));
    __shared__ float wm[2];
    if ((co & 63) == 0) wm[co >> 6] = m;
    __syncthreads();
    m = fmaxf(wm[0], wm[1]);

    float e = __expf(pooled - m);
#pragma unroll
    for (int off = 32; off > 0; off >>= 1)
        e += __shfl_xor(e, off, 64);
    __shared__ float wl[2];
    if ((co & 63) == 0) wl[co >> 6] = e;
    __syncthreads();
    if (co == 0) out[n] = 10.0f * (m + logf(wl[0] + wl[1]));
}

extern "C" void kernel_launch(void* const* d_in, const int* in_sizes, int n_in,
                              void* d_out, int out_size, void* d_ws, size_t ws_size,
                              hipStream_t stream) {
    const float* x          = (const float*)d_in[0];
    const float* weight     = (const float*)d_in[1];
    const float* conv_bias  = (const float*)d_in[2];
    const float* extra_bias = (const float*)d_in[3];
    float* out = (float*)d_out;

    float* Sx = (float*)d_ws;          // 2048 floats
    float* Sw = Sx + PLANES;           // 8192 floats

    stage1_kernel<<<PLANES + WBLKS, 256, 0, stream>>>(x, weight, Sx, Sw);
    final_kernel<<<Nn, 128, 0, stream>>>(Sx, Sw, conv_bias, extra_bias, out);
}